// Round 1
// baseline (443.774 us; speedup 1.0000x reference)
//
#include <hip/hip_runtime.h>

// Problem constants (fixed by the reference's setup_inputs).
#define CIN  128
#define COUT 128

// Precompute cs[o] = sum_c W[c,o]  and  bdot[o] = sum_c bias[c] * W[c,o].
// W is (COUT_in=128, COUT_out=128) row-major; thread o walks column o
// (consecutive o -> consecutive addresses per iteration: coalesced).
__global__ void colsum_kernel(const float* __restrict__ W,
                              const float* __restrict__ bias,
                              float* __restrict__ cs,
                              float* __restrict__ bdot) {
    const int o = threadIdx.x;  // 0..COUT-1
    float s = 0.f, b = 0.f;
    for (int c = 0; c < CIN; ++c) {
        const float w = W[c * COUT + o];
        s += w;
        b += bias[c] * w;
    }
    cs[o]   = s;
    bdot[o] = b;
}

// Main kernel: out[p*128 + o] = S(p) * cs[o] + bdot[o],
// where S(p) = sum over the 128 input channels of pixel p.
// One 32-lane half-wave per pixel; lane j handles channels [4j, 4j+4).
__global__ __launch_bounds__(256) void convoffset_kernel(
    const float* __restrict__ in,
    const float* __restrict__ cs,
    const float* __restrict__ bdot,
    float* __restrict__ out,
    int npix)
{
    const int lane        = threadIdx.x & 31;      // lane within half-wave
    const int hw_in_block = threadIdx.x >> 5;      // half-wave id in block
    const int hw_per_blk  = blockDim.x >> 5;       // 8 for blockDim=256
    const int hw_id       = blockIdx.x * hw_per_blk + hw_in_block;
    const int hw_total    = gridDim.x * hw_per_blk;

    // Loop-invariant per-lane constants (4 consecutive output channels).
    const float4 cs4 = reinterpret_cast<const float4*>(cs)[lane];
    const float4 bd4 = reinterpret_cast<const float4*>(bdot)[lane];

    for (int p = hw_id; p < npix; p += hw_total) {
        const size_t base = (size_t)p * CIN;
        const float4 v = reinterpret_cast<const float4*>(in + base)[lane];
        float s = (v.x + v.y) + (v.z + v.w);
        // Butterfly reduce across the 32-lane segment.
        #pragma unroll
        for (int off = 16; off > 0; off >>= 1)
            s += __shfl_xor(s, off, 32);
        float4 o4;
        o4.x = s * cs4.x + bd4.x;
        o4.y = s * cs4.y + bd4.y;
        o4.z = s * cs4.z + bd4.z;
        o4.w = s * cs4.w + bd4.w;
        reinterpret_cast<float4*>(out + base)[lane] = o4;
    }
}

extern "C" void kernel_launch(void* const* d_in, const int* in_sizes, int n_in,
                              void* d_out, int out_size, void* d_ws, size_t ws_size,
                              hipStream_t stream) {
    // setup_inputs order: inputs, kernel, bias, W
    const float* in   = (const float*)d_in[0];
    // d_in[1] is the conv kernel: structurally a center-tap all-ones matrix
    // (see reference) -> conv == per-pixel channel sum, broadcast over cout.
    const float* bias = (const float*)d_in[2];
    const float* W    = (const float*)d_in[3];
    float* out = (float*)d_out;

    float* cs   = (float*)d_ws;   // [COUT]
    float* bdot = cs + COUT;      // [COUT]

    colsum_kernel<<<1, COUT, 0, stream>>>(W, bias, cs, bdot);

    const int npix = in_sizes[0] / CIN;  // 8*256*256 = 524288
    // 8192 blocks * 8 half-waves = 65536 pixel workers; 8 pixels each.
    convoffset_kernel<<<8192, 256, 0, stream>>>(in, cs, bdot, out, npix);
}